// Round 4
// baseline (1298.547 us; speedup 1.0000x reference)
//
#include <hip/hip_runtime.h>
#include <cstddef>
#include <cstdint>
#include <cmath>

#define LDIM 8000
#define KNB  48
#define HDIM 128

typedef short  bf16x8 __attribute__((ext_vector_type(8)));
typedef float  f32x4  __attribute__((ext_vector_type(4)));

__device__ __forceinline__ float gelu_f(float x) {
    return 0.5f * x * (1.0f + erff(x * 0.70710678118654752440f));
}
__device__ __forceinline__ unsigned short bf16_rne(float x) {
    unsigned u = __float_as_uint(x);
    return (unsigned short)((u + 0x7FFFu + ((u >> 16) & 1u)) >> 16);
}
__device__ __forceinline__ float bf16_f(unsigned short h) {
    return __uint_as_float((unsigned)h << 16);
}
__device__ __forceinline__ void split2(float x, short& h, short& l) {
    unsigned short hb = bf16_rne(x);
    h = (short)hb;
    l = (short)bf16_rne(x - bf16_f(hb));
}
__device__ __forceinline__ void mm3(f32x4& c, bf16x8 ah, bf16x8 al, bf16x8 bh, bf16x8 bl) {
    c = __builtin_amdgcn_mfma_f32_16x16x32_bf16(ah, bh, c, 0, 0, 0);
    c = __builtin_amdgcn_mfma_f32_16x16x32_bf16(ah, bl, c, 0, 0, 0);
    c = __builtin_amdgcn_mfma_f32_16x16x32_bf16(al, bh, c, 0, 0, 0);
}

// ---------------------------------------------------------------------------
// Prep: W[K][128] fp32 -> transposed split planes: hi[128][K], lo[128][K] bf16
// ---------------------------------------------------------------------------
__global__ void wsplit_kernel(const float* __restrict__ W, short* __restrict__ dst, int K) {
    int t = blockIdx.x * 256 + threadIdx.x;
    if (t >= K * 128) return;
    int k = t >> 7, n = t & 127;
    float x = W[t];
    short h, l; split2(x, h, l);
    dst[(size_t)n * K + k]         = h;   // hi plane
    dst[(size_t)(128 + n) * K + k] = l;   // lo plane
}

// ---------------------------------------------------------------------------
// MFMA message kernel: 1 block = 2 nodes (96 neighbor rows), 4 waves.
// 3-layer MLP on X = [hv | hE | hv[Eidx]] (96x384 -> 96x128) via split-bf16
// MFMA (3 mfma per product: hi*hi + hi*lo + lo*hi ~ fp32 accuracy).
// EDGE=false: masked row-sum /30 -> dh[L][128]. EDGE=true: LN(hE+m2) -> out.
// Wave w owns output cols [w*32, w*32+32) for all 96 rows (6 m-tiles x 2 n-tiles).
// ---------------------------------------------------------------------------
template<bool EDGE>
__global__ __launch_bounds__(256, 2)
void msg_mfma_kernel(const float* __restrict__ hv_src,
                     const float* __restrict__ hEin,
                     const int*   __restrict__ Eidx,
                     const float* __restrict__ mask_att,   // node only
                     const short* __restrict__ WaT,        // [2][128][384] bf16 planes
                     const short* __restrict__ WbT,        // [2][128][128]
                     const short* __restrict__ WcT,        // [2][128][128]
                     const float* __restrict__ ba,
                     const float* __restrict__ bb,
                     const float* __restrict__ bc,
                     const float* __restrict__ ln_s,       // edge only
                     const float* __restrict__ ln_o,
                     float* __restrict__ outp)
{
    // Xc (L1 staging) and Cp (inter-layer acts) have disjoint, barrier-separated
    // lifetimes -> union. Row pads: Xc 40 shorts (80B=5*16) and Cp 136 shorts
    // (272B=17*16) keep ds_read_b128 16B-aligned and granule-spread.
    __shared__ union {
        short xc[2][96][40];    // 15,360 B  (hi/lo planes of 96x32 X chunk)
        short cp[2][96][136];   // 52,224 B  (hi/lo planes of 96x128 C)
        float xb[96 * 132];     // 50,688 B  (EDGE: fp32 residual+m2 for LN)
    } sm;
    __shared__ float mask_s[96];

    const int bid  = blockIdx.x;
    const int n0   = bid * 2;            // node of rows 0..47 (rows 48..95 -> n0+1)
    const int tid  = threadIdx.x;
    const int w    = tid >> 6;           // wave 0..3
    const int lane = tid & 63;
    const int lr   = lane & 15;          // A: M-row within tile; B/D: N-col
    const int hgr  = lane >> 4;          // k-group (inputs) / row-group (output)
    const int colA = w * 32 + lr;        // n-tile 0 col
    const int colB = colA + 16;          // n-tile 1 col

    if constexpr (!EDGE) {
        if (tid < 96) mask_s[tid] = mask_att[(size_t)n0 * KNB + tid];
    }

    // staging task descriptors: 768 (row, col-quad) tasks, 3 per thread
    int trow[3], tq[3];
    const float* pV[3]; const float* pE[3]; const float* pN[3];
#pragma unroll
    for (int it = 0; it < 3; it++) {
        const int t   = tid + it * 256;
        const int row = t >> 3, q = t & 7;
        trow[it] = row; tq[it] = q;
        const int node = n0 + (row >= 48 ? 1 : 0);
        pV[it] = hv_src + (size_t)node * HDIM + q * 4;
        pE[it] = hEin + ((size_t)n0 * KNB + row) * HDIM + q * 4;
        const int nb = Eidx[n0 * KNB + row];
        pN[it] = hv_src + (size_t)nb * HDIM + q * 4;
    }

    f32x4 acc[12];   // [mt][nt]: rows mt*16 + hgr*4 + j, col w*32 + nt*16 + lr

    // ======== layer 1: gelu(X @ Wa + ba), K = 384 ========
    {
        const float bA = ba[colA], bB = ba[colB];
#pragma unroll
        for (int mt = 0; mt < 6; mt++) {
            acc[mt*2+0] = (f32x4){bA, bA, bA, bA};
            acc[mt*2+1] = (f32x4){bB, bB, bB, bB};
        }
    }
    {
        const short* WaL = WaT + 128 * 384;
#pragma unroll 1
        for (int ks = 0; ks < 12; ks++) {
            const int ko = ks * 32 + hgr * 8;
            bf16x8 bh0 = *(const bf16x8*)(WaT + (size_t)colA * 384 + ko);
            bf16x8 bl0 = *(const bf16x8*)(WaL + (size_t)colA * 384 + ko);
            bf16x8 bh1 = *(const bf16x8*)(WaT + (size_t)colB * 384 + ko);
            bf16x8 bl1 = *(const bf16x8*)(WaL + (size_t)colB * 384 + ko);
            __syncthreads();   // previous iteration's Xc reads complete
            // stage X chunk (cols ks*32..ks*32+31) as bf16 hi/lo
            {
                const int seg = ks >> 2, co = (ks & 3) * 32;
#pragma unroll
                for (int it = 0; it < 3; it++) {
                    const float* p = (seg == 0) ? pV[it] : (seg == 1) ? pE[it] : pN[it];
                    const float4 v = *(const float4*)(p + co);
                    short h0,l0,h1,l1,h2,l2,h3,l3;
                    split2(v.x,h0,l0); split2(v.y,h1,l1);
                    split2(v.z,h2,l2); split2(v.w,h3,l3);
                    *(short4*)&sm.xc[0][trow[it]][tq[it]*4] = make_short4(h0,h1,h2,h3);
                    *(short4*)&sm.xc[1][trow[it]][tq[it]*4] = make_short4(l0,l1,l2,l3);
                }
            }
            __syncthreads();
#pragma unroll
            for (int mt = 0; mt < 6; mt++) {
                bf16x8 ah = *(const bf16x8*)&sm.xc[0][mt*16 + lr][hgr*8];
                bf16x8 al = *(const bf16x8*)&sm.xc[1][mt*16 + lr][hgr*8];
                mm3(acc[mt*2+0], ah, al, bh0, bl0);
                mm3(acc[mt*2+1], ah, al, bh1, bl1);
            }
        }
    }
    __syncthreads();   // Xc dead; union region becomes Cp
#pragma unroll
    for (int mt = 0; mt < 6; mt++)
#pragma unroll
    for (int nt = 0; nt < 2; nt++) {
        const int col = w*32 + nt*16 + lr;
        const f32x4 a = acc[mt*2+nt];
#pragma unroll
        for (int j = 0; j < 4; j++) {
            const int row = mt*16 + hgr*4 + j;
            short h, l; split2(gelu_f(a[j]), h, l);
            sm.cp[0][row][col] = h;
            sm.cp[1][row][col] = l;
        }
    }
    __syncthreads();

    // ======== layer 2: gelu(C1 @ Wb + bb), K = 128 ========
    {
        const short* WbL = WbT + 128 * 128;
        const float bA = bb[colA], bB = bb[colB];
#pragma unroll
        for (int mt = 0; mt < 6; mt++) {
            acc[mt*2+0] = (f32x4){bA, bA, bA, bA};
            acc[mt*2+1] = (f32x4){bB, bB, bB, bB};
        }
#pragma unroll 1
        for (int ks = 0; ks < 4; ks++) {
            const int ko = ks * 32 + hgr * 8;
            bf16x8 bh0 = *(const bf16x8*)(WbT + (size_t)colA * 128 + ko);
            bf16x8 bl0 = *(const bf16x8*)(WbL + (size_t)colA * 128 + ko);
            bf16x8 bh1 = *(const bf16x8*)(WbT + (size_t)colB * 128 + ko);
            bf16x8 bl1 = *(const bf16x8*)(WbL + (size_t)colB * 128 + ko);
#pragma unroll
            for (int mt = 0; mt < 6; mt++) {
                bf16x8 ah = *(const bf16x8*)&sm.cp[0][mt*16 + lr][ko];
                bf16x8 al = *(const bf16x8*)&sm.cp[1][mt*16 + lr][ko];
                mm3(acc[mt*2+0], ah, al, bh0, bl0);
                mm3(acc[mt*2+1], ah, al, bh1, bl1);
            }
        }
        __syncthreads();   // all C1 reads complete before overwrite
#pragma unroll
        for (int mt = 0; mt < 6; mt++)
#pragma unroll
        for (int nt = 0; nt < 2; nt++) {
            const int col = w*32 + nt*16 + lr;
            const f32x4 a = acc[mt*2+nt];
#pragma unroll
            for (int j = 0; j < 4; j++) {
                const int row = mt*16 + hgr*4 + j;
                short h, l; split2(gelu_f(a[j]), h, l);
                sm.cp[0][row][col] = h;
                sm.cp[1][row][col] = l;
            }
        }
        __syncthreads();
    }

    // ======== layer 3: C2 @ Wc + bc (no activation), K = 128 ========
    {
        const short* WcL = WcT + 128 * 128;
        const float bA = bc[colA], bB = bc[colB];
#pragma unroll
        for (int mt = 0; mt < 6; mt++) {
            acc[mt*2+0] = (f32x4){bA, bA, bA, bA};
            acc[mt*2+1] = (f32x4){bB, bB, bB, bB};
        }
#pragma unroll 1
        for (int ks = 0; ks < 4; ks++) {
            const int ko = ks * 32 + hgr * 8;
            bf16x8 bh0 = *(const bf16x8*)(WcT + (size_t)colA * 128 + ko);
            bf16x8 bl0 = *(const bf16x8*)(WcL + (size_t)colA * 128 + ko);
            bf16x8 bh1 = *(const bf16x8*)(WcT + (size_t)colB * 128 + ko);
            bf16x8 bl1 = *(const bf16x8*)(WcL + (size_t)colB * 128 + ko);
#pragma unroll
            for (int mt = 0; mt < 6; mt++) {
                bf16x8 ah = *(const bf16x8*)&sm.cp[0][mt*16 + lr][ko];
                bf16x8 al = *(const bf16x8*)&sm.cp[1][mt*16 + lr][ko];
                mm3(acc[mt*2+0], ah, al, bh0, bl0);
                mm3(acc[mt*2+1], ah, al, bh1, bl1);
            }
        }
        __syncthreads();   // all C2 reads complete (EDGE overlays Cp next)
    }

    if constexpr (!EDGE) {
        // masked sum over each node's 48 rows -> dh[node][col] = sum/30
        float s[4] = {0.f, 0.f, 0.f, 0.f};   // [node][nt]
#pragma unroll
        for (int mt = 0; mt < 6; mt++) {
            const int nodei = (mt >= 3) ? 1 : 0;
#pragma unroll
            for (int j = 0; j < 4; j++) {
                const float m = mask_s[mt*16 + hgr*4 + j];
                s[nodei*2+0] = fmaf(m, acc[mt*2+0][j], s[nodei*2+0]);
                s[nodei*2+1] = fmaf(m, acc[mt*2+1][j], s[nodei*2+1]);
            }
        }
#pragma unroll
        for (int i = 0; i < 4; i++) {
            s[i] += __shfl_xor(s[i], 16, 64);
            s[i] += __shfl_xor(s[i], 32, 64);
        }
        if (lane < 16) {
            outp[(size_t)n0 * HDIM + colA]       = s[0] * (1.0f / 30.0f);
            outp[(size_t)n0 * HDIM + colB]       = s[1] * (1.0f / 30.0f);
            outp[(size_t)(n0+1) * HDIM + colA]   = s[2] * (1.0f / 30.0f);
            outp[(size_t)(n0+1) * HDIM + colB]   = s[3] * (1.0f / 30.0f);
        }
    } else {
        // x = h_E + m2 -> LDS fp32, then per-row LN with n3
#pragma unroll
        for (int mt = 0; mt < 6; mt++)
#pragma unroll
        for (int nt = 0; nt < 2; nt++) {
            const int col = w*32 + nt*16 + lr;
            const f32x4 a = acc[mt*2+nt];
#pragma unroll
            for (int j = 0; j < 4; j++) {
                const int row = mt*16 + hgr*4 + j;
                const float he = hEin[((size_t)n0 * KNB + row) * HDIM + col];
                sm.xb[row * 132 + col] = a[j] + he;
            }
        }
        __syncthreads();
        for (int r = w; r < 96; r += 4) {
            const float x0 = sm.xb[r * 132 + lane];
            const float x1 = sm.xb[r * 132 + 64 + lane];
            float su = x0 + x1;
#pragma unroll
            for (int off = 32; off; off >>= 1) su += __shfl_xor(su, off, 64);
            const float mu = su * (1.0f / 128.0f);
            const float d0 = x0 - mu, d1 = x1 - mu;
            float v = d0 * d0 + d1 * d1;
#pragma unroll
            for (int off = 32; off; off >>= 1) v += __shfl_xor(v, off, 64);
            const float rs = rsqrtf(v * (1.0f / 128.0f) + 1e-5f);
            const size_t base = ((size_t)n0 * KNB + r) * HDIM;
            outp[base + lane]      = d0 * rs * ln_s[lane]      + ln_o[lane];
            outp[base + 64 + lane] = d1 * rs * ln_s[64 + lane] + ln_o[64 + lane];
        }
    }
}

// ---------------------------------------------------------------------------
// K2 (fast path): LN1(hV + dh) -> FFN -> LN2 -> mask. fp32 (2% of FLOPs).
// ---------------------------------------------------------------------------
template<int RT, int KDIM>
__device__ __forceinline__ void gemm_block(
    const float* __restrict__ A, const int lda,
    const float* __restrict__ Wg, const int wstride,
    float* __restrict__ Wst,
    float acc[RT][4], const int rg, const int jg, const int tid)
{
#pragma unroll 1
    for (int ci = 0; ci < KDIM / 32; ci++) {
        __syncthreads();
#pragma unroll
        for (int e = tid; e < 1024; e += 256) {
            const int i  = e >> 5;
            const int j4 = (e & 31) << 2;
            *(float4*)(Wst + i * 128 + j4) =
                *(const float4*)(Wg + (size_t)(ci * 32 + i) * wstride + j4);
        }
        __syncthreads();
#pragma unroll
        for (int ii = 0; ii < 32; ii += 4) {
            float4 xr[RT];
#pragma unroll
            for (int rr = 0; rr < RT; rr++)
                xr[rr] = *(const float4*)(A + (rg * RT + rr) * lda + ci * 32 + ii);
#pragma unroll
            for (int q = 0; q < 4; q++) {
                const float4 wv = *(const float4*)(Wst + (ii + q) * 128 + (jg << 2));
#pragma unroll
                for (int rr = 0; rr < RT; rr++) {
                    const float x = (q == 0) ? xr[rr].x : (q == 1) ? xr[rr].y
                                  : (q == 2) ? xr[rr].z : xr[rr].w;
                    acc[rr][0] = fmaf(x, wv.x, acc[rr][0]);
                    acc[rr][1] = fmaf(x, wv.y, acc[rr][1]);
                    acc[rr][2] = fmaf(x, wv.z, acc[rr][2]);
                    acc[rr][3] = fmaf(x, wv.w, acc[rr][3]);
                }
            }
        }
    }
}

template<int NPART>
__global__ __launch_bounds__(256, 2)
void node_update_kernel(const float* __restrict__ hV,
                        const float* __restrict__ dhp,   // [L][NPART][128]
                        const float* __restrict__ maskV,
                        const float* __restrict__ Wi, const float* __restrict__ bi,
                        const float* __restrict__ Wo, const float* __restrict__ bo,
                        const float* __restrict__ n1s, const float* __restrict__ n1o,
                        const float* __restrict__ n2s, const float* __restrict__ n2o,
                        float* __restrict__ outp)
{
    __shared__ float hv1[32 * 128];
    __shared__ float Wst[32 * 128];
    __shared__ float tb[32 * 128];

    const int l0  = blockIdx.x * 32;
    const int tid = threadIdx.x;
    const int w = tid >> 6, ln = tid & 63;

    for (int r = w; r < 32; r += 4) {
        const int l = l0 + r;
        const size_t b = (size_t)l * 128;
        float x0 = hV[b + ln], x1 = hV[b + 64 + ln];
#pragma unroll
        for (int p = 0; p < NPART; p++) {
            x0 += dhp[((size_t)l * NPART + p) * 128 + ln];
            x1 += dhp[((size_t)l * NPART + p) * 128 + 64 + ln];
        }
        float s = x0 + x1;
#pragma unroll
        for (int off = 32; off; off >>= 1) s += __shfl_xor(s, off, 64);
        const float mu = s * (1.0f / 128.0f);
        const float d0 = x0 - mu, d1 = x1 - mu;
        float v = d0 * d0 + d1 * d1;
#pragma unroll
        for (int off = 32; off; off >>= 1) v += __shfl_xor(v, off, 64);
        const float rs = rsqrtf(v * (1.0f / 128.0f) + 1e-5f);
        hv1[r * 128 + ln]      = d0 * rs * n1s[ln]      + n1o[ln];
        hv1[r * 128 + 64 + ln] = d1 * rs * n1s[64 + ln] + n1o[64 + ln];
    }

    const int rg = tid >> 5, jg = tid & 31;
    float dacc[4][4];
#pragma unroll
    for (int rr = 0; rr < 4; rr++)
#pragma unroll
        for (int q = 0; q < 4; q++) dacc[rr][q] = bo[(jg << 2) + q];

#pragma unroll 1
    for (int hc = 0; hc < 4; hc++) {
        float tacc[4][4];
#pragma unroll
        for (int rr = 0; rr < 4; rr++)
#pragma unroll
            for (int q = 0; q < 4; q++) tacc[rr][q] = bi[hc * 128 + (jg << 2) + q];
        gemm_block<4, 128>(hv1, 128, Wi + hc * 128, 512, Wst, tacc, rg, jg, tid);
        __syncthreads();
#pragma unroll
        for (int rr = 0; rr < 4; rr++)
#pragma unroll
            for (int q = 0; q < 4; q++)
                tb[(rg * 4 + rr) * 128 + (jg << 2) + q] = gelu_f(tacc[rr][q]);
        gemm_block<4, 128>(tb, 128, Wo + (size_t)hc * 128 * 128, 128, Wst, dacc, rg, jg, tid);
    }
    __syncthreads();
#pragma unroll
    for (int rr = 0; rr < 4; rr++)
#pragma unroll
        for (int q = 0; q < 4; q++)
            tb[(rg * 4 + rr) * 128 + (jg << 2) + q] = dacc[rr][q];
    __syncthreads();

    for (int r = w; r < 32; r += 4) {
        const int l = l0 + r;
        const float x0 = hv1[r * 128 + ln]      + tb[r * 128 + ln];
        const float x1 = hv1[r * 128 + 64 + ln] + tb[r * 128 + 64 + ln];
        float s = x0 + x1;
#pragma unroll
        for (int off = 32; off; off >>= 1) s += __shfl_xor(s, off, 64);
        const float mu = s * (1.0f / 128.0f);
        const float d0 = x0 - mu, d1 = x1 - mu;
        float v = d0 * d0 + d1 * d1;
#pragma unroll
        for (int off = 32; off; off >>= 1) v += __shfl_xor(v, off, 64);
        const float rs = rsqrtf(v * (1.0f / 128.0f) + 1e-5f);
        const float mv = maskV[l];
        outp[(size_t)l * 128 + ln]      = mv * (d0 * rs * n2s[ln]      + n2o[ln]);
        outp[(size_t)l * 128 + 64 + ln] = mv * (d1 * rs * n2s[64 + ln] + n2o[64 + ln]);
    }
}

// ---------------------------------------------------------------------------
// Fallback fp32 message kernel (used only if ws_size is too small).
// ---------------------------------------------------------------------------
template<bool EDGE>
__global__ __launch_bounds__(256, 2)
void msg_kernel(const float* __restrict__ hv_src,
                const float* __restrict__ hEin,
                const int*   __restrict__ Eidx,
                const float* __restrict__ mask_att,
                const float* __restrict__ Wa, const float* __restrict__ ba,
                const float* __restrict__ Wb, const float* __restrict__ bb,
                const float* __restrict__ Wc3, const float* __restrict__ bc,
                const float* __restrict__ ln_s, const float* __restrict__ ln_o,
                float* __restrict__ outp)
{
    __shared__ float xs[24 * 384];
    __shared__ float Wst[32 * 128];
    __shared__ float Cb[24 * 128];

    const int bid = blockIdx.x;
    const int l   = bid >> 1;
    const int k0  = (bid & 1) * 24;
    const int tid = threadIdx.x;

#pragma unroll
    for (int e = tid; e < 24 * 32; e += 256) {
        const int r  = e >> 5;
        const int c4 = (e & 31) << 2;
        const int k  = k0 + r;
        const int nidx = Eidx[l * KNB + k];
        const float4 hv4 = *(const float4*)(hv_src + (size_t)l * HDIM + c4);
        const float4 he4 = *(const float4*)(hEin + ((size_t)l * KNB + k) * HDIM + c4);
        const float4 nb4 = *(const float4*)(hv_src + (size_t)nidx * HDIM + c4);
        *(float4*)(xs + r * 384 +       c4) = hv4;
        *(float4*)(xs + r * 384 + 128 + c4) = he4;
        *(float4*)(xs + r * 384 + 256 + c4) = nb4;
    }

    const int rg = tid >> 5;
    const int jg = tid & 31;
    float acc[3][4];

#pragma unroll
    for (int rr = 0; rr < 3; rr++)
#pragma unroll
        for (int q = 0; q < 4; q++) acc[rr][q] = ba[(jg << 2) + q];
    gemm_block<3, 384>(xs, 384, Wa, 128, Wst, acc, rg, jg, tid);
    __syncthreads();
#pragma unroll
    for (int rr = 0; rr < 3; rr++)
#pragma unroll
        for (int q = 0; q < 4; q++)
            Cb[(rg * 3 + rr) * 128 + (jg << 2) + q] = gelu_f(acc[rr][q]);

#pragma unroll
    for (int rr = 0; rr < 3; rr++)
#pragma unroll
        for (int q = 0; q < 4; q++) acc[rr][q] = bb[(jg << 2) + q];
    gemm_block<3, 128>(Cb, 128, Wb, 128, Wst, acc, rg, jg, tid);
    __syncthreads();
#pragma unroll
    for (int rr = 0; rr < 3; rr++)
#pragma unroll
        for (int q = 0; q < 4; q++)
            Cb[(rg * 3 + rr) * 128 + (jg << 2) + q] = gelu_f(acc[rr][q]);

#pragma unroll
    for (int rr = 0; rr < 3; rr++)
#pragma unroll
        for (int q = 0; q < 4; q++) acc[rr][q] = bc[(jg << 2) + q];
    gemm_block<3, 128>(Cb, 128, Wc3, 128, Wst, acc, rg, jg, tid);
    __syncthreads();

    if constexpr (!EDGE) {
        float psum[4] = {0.f, 0.f, 0.f, 0.f};
#pragma unroll
        for (int rr = 0; rr < 3; rr++) {
            const int k = k0 + rg * 3 + rr;
            const float mval = mask_att[l * KNB + k];
#pragma unroll
            for (int q = 0; q < 4; q++) psum[q] = fmaf(mval, acc[rr][q], psum[q]);
        }
#pragma unroll
        for (int q = 0; q < 4; q++) Cb[rg * 128 + (jg << 2) + q] = psum[q];
        __syncthreads();
        if (tid < 128) {
            float s = 0.f;
#pragma unroll
            for (int g = 0; g < 8; g++) s += Cb[g * 128 + tid];
            outp[(size_t)bid * 128 + tid] = s * (1.0f / 30.0f);
        }
    } else {
#pragma unroll
        for (int rr = 0; rr < 3; rr++)
#pragma unroll
            for (int q = 0; q < 4; q++)
                Cb[(rg * 3 + rr) * 128 + (jg << 2) + q] = acc[rr][q];
        __syncthreads();
        const int w = tid >> 6, ln = tid & 63;
        for (int r = w; r < 24; r += 4) {
            const float x0 = Cb[r * 128 + ln]      + xs[r * 384 + 128 + ln];
            const float x1 = Cb[r * 128 + 64 + ln] + xs[r * 384 + 192 + ln];
            float s = x0 + x1;
#pragma unroll
            for (int off = 32; off; off >>= 1) s += __shfl_xor(s, off, 64);
            const float mu = s * (1.0f / 128.0f);
            const float d0 = x0 - mu, d1 = x1 - mu;
            float v = d0 * d0 + d1 * d1;
#pragma unroll
            for (int off = 32; off; off >>= 1) v += __shfl_xor(v, off, 64);
            const float rs = rsqrtf(v * (1.0f / 128.0f) + 1e-5f);
            const size_t base = ((size_t)(l * KNB + k0 + r)) * 128;
            outp[base + ln]      = d0 * rs * ln_s[ln]      + ln_o[ln];
            outp[base + 64 + ln] = d1 * rs * ln_s[64 + ln] + ln_o[64 + ln];
        }
    }
}

extern "C" void kernel_launch(void* const* d_in, const int* in_sizes, int n_in,
                              void* d_out, int out_size, void* d_ws, size_t ws_size,
                              hipStream_t stream) {
    const float* hV      = (const float*)d_in[0];
    const float* hE      = (const float*)d_in[1];
    const int*   Eidx    = (const int*)  d_in[2];
    const float* maskV   = (const float*)d_in[3];
    const float* maskAtt = (const float*)d_in[4];
    const float* W1  = (const float*)d_in[5];  const float* b1  = (const float*)d_in[6];
    const float* W2  = (const float*)d_in[7];  const float* b2  = (const float*)d_in[8];
    const float* W3  = (const float*)d_in[9];  const float* b3  = (const float*)d_in[10];
    const float* W11 = (const float*)d_in[11]; const float* b11 = (const float*)d_in[12];
    const float* W12 = (const float*)d_in[13]; const float* b12 = (const float*)d_in[14];
    const float* W13 = (const float*)d_in[15]; const float* b13 = (const float*)d_in[16];
    const float* Wi  = (const float*)d_in[17]; const float* bi  = (const float*)d_in[18];
    const float* Wo  = (const float*)d_in[19]; const float* bo  = (const float*)d_in[20];
    const float* n1s = (const float*)d_in[21]; const float* n1o = (const float*)d_in[22];
    const float* n2s = (const float*)d_in[23]; const float* n2o = (const float*)d_in[24];
    const float* n3s = (const float*)d_in[25]; const float* n3o = (const float*)d_in[26];

    float* outF  = (float*)d_out;
    float* hVout = outF;                          // [L][128]
    float* hEout = outF + (size_t)LDIM * HDIM;    // [L][48][128]

    // ws layout (fast path): 6 transposed split-bf16 weight planes + dh buffer
    const size_t O_W1T  = 0;          // [2][128][384] bf16 = 196608 B
    const size_t O_W2T  = 196608;     // [2][128][128] bf16 =  65536 B
    const size_t O_W3T  = 262144;
    const size_t O_W11T = 327680;
    const size_t O_W12T = 524288;
    const size_t O_W13T = 589824;
    const size_t O_DH   = 655360;     // [L][128] f32 = 4096000 B
    const size_t WS_NEED = O_DH + (size_t)LDIM * HDIM * sizeof(float);  // 4,751,360

    if (ws_size >= WS_NEED) {
        char* wsb = (char*)d_ws;
        short* W1T  = (short*)(wsb + O_W1T);
        short* W2T  = (short*)(wsb + O_W2T);
        short* W3T  = (short*)(wsb + O_W3T);
        short* W11T = (short*)(wsb + O_W11T);
        short* W12T = (short*)(wsb + O_W12T);
        short* W13T = (short*)(wsb + O_W13T);
        float* dh   = (float*)(wsb + O_DH);

        wsplit_kernel<<<192, 256, 0, stream>>>(W1,  W1T,  384);
        wsplit_kernel<<< 64, 256, 0, stream>>>(W2,  W2T,  128);
        wsplit_kernel<<< 64, 256, 0, stream>>>(W3,  W3T,  128);
        wsplit_kernel<<<192, 256, 0, stream>>>(W11, W11T, 384);
        wsplit_kernel<<< 64, 256, 0, stream>>>(W12, W12T, 128);
        wsplit_kernel<<< 64, 256, 0, stream>>>(W13, W13T, 128);

        msg_mfma_kernel<false><<<LDIM / 2, 256, 0, stream>>>(
            hV, hE, Eidx, maskAtt, W1T, W2T, W3T, b1, b2, b3, nullptr, nullptr, dh);

        node_update_kernel<1><<<LDIM / 32, 256, 0, stream>>>(
            hV, dh, maskV, Wi, bi, Wo, bo, n1s, n1o, n2s, n2o, hVout);

        msg_mfma_kernel<true><<<LDIM / 2, 256, 0, stream>>>(
            hVout, hE, Eidx, nullptr, W11T, W12T, W13T, b11, b12, b13, n3s, n3o, hEout);
    } else {
        // fallback: pure fp32 path; dh partials in ws if possible else hE region
        const size_t dh_bytes = (size_t)LDIM * 2 * HDIM * sizeof(float);
        float* dhp = (ws_size >= dh_bytes) ? (float*)d_ws : hEout;

        msg_kernel<false><<<LDIM * 2, 256, 0, stream>>>(
            hV, hE, Eidx, maskAtt, W1, b1, W2, b2, W3, b3, nullptr, nullptr, dhp);

        node_update_kernel<2><<<LDIM / 32, 256, 0, stream>>>(
            hV, dhp, maskV, Wi, bi, Wo, bo, n1s, n1o, n2s, n2o, hVout);

        msg_kernel<true><<<LDIM * 2, 256, 0, stream>>>(
            hVout, hE, Eidx, nullptr, W11, b11, W12, b12, W13, b13, n3s, n3o, hEout);
    }
}

// Round 7
// 1164.473 us; speedup vs baseline: 1.1151x; 1.1151x over previous
//
#include <hip/hip_runtime.h>
#include <cstddef>
#include <cstdint>
#include <cmath>

#define LDIM 8000
#define KNB  48
#define HDIM 128

typedef short  bf16x8 __attribute__((ext_vector_type(8)));
typedef float  f32x4  __attribute__((ext_vector_type(4)));

__device__ __forceinline__ float gelu_f(float x) {
    return 0.5f * x * (1.0f + erff(x * 0.70710678118654752440f));
}
__device__ __forceinline__ unsigned short bf16_rne(float x) {
    unsigned u = __float_as_uint(x);
    return (unsigned short)((u + 0x7FFFu + ((u >> 16) & 1u)) >> 16);
}
__device__ __forceinline__ float bf16_f(unsigned short h) {
    return __uint_as_float((unsigned)h << 16);
}
__device__ __forceinline__ void split2(float x, short& h, short& l) {
    unsigned short hb = bf16_rne(x);
    h = (short)hb;
    l = (short)bf16_rne(x - bf16_f(hb));
}
__device__ __forceinline__ void mm3(f32x4& c, bf16x8 ah, bf16x8 al, bf16x8 bh, bf16x8 bl) {
    c = __builtin_amdgcn_mfma_f32_16x16x32_bf16(ah, bh, c, 0, 0, 0);
    c = __builtin_amdgcn_mfma_f32_16x16x32_bf16(ah, bl, c, 0, 0, 0);
    c = __builtin_amdgcn_mfma_f32_16x16x32_bf16(al, bh, c, 0, 0, 0);
}

// W[K][128] fp32 -> transposed split planes hi[128][K], lo[128][K]
__global__ void wsplit_kernel(const float* __restrict__ W, short* __restrict__ dst, int K) {
    int t = blockIdx.x * 256 + threadIdx.x;
    if (t >= K * 128) return;
    int k = t >> 7, n = t & 127;
    short h, l; split2(W[t], h, l);
    dst[(size_t)n * K + k]         = h;
    dst[(size_t)(128 + n) * K + k] = l;
}

// hv[L][128] fp32 -> planes hi[L*128], lo[L*128]
__global__ void hvsplit_kernel(const float* __restrict__ src, short* __restrict__ dst) {
    int t = blockIdx.x * 256 + threadIdx.x;
    if (t >= LDIM * HDIM) return;
    short h, l; split2(src[t], h, l);
    dst[t] = h;
    dst[LDIM * HDIM + t] = l;
}

// ---------------------------------------------------------------------------
// MFMA message kernel. 1 block = 2 nodes (96 rows), 4 waves, wave owns 32 cols.
// Cp rows stored physically permuted by pi(r) (within each 16-row tile):
//   pi(r) = ((r&2)<<2) | ((2*(r>>2) + (r&1) + 2*(r&2)) & 7)
// Derived so that (a) ds_read_b128 A-frag reads stay phase-perfect (pi mod 8
// bijective on each 8-row half) and (b) the boundary b16 write scatter's four
// hgr row-groups land on disjoint 8-bank octets (conflict-free both sides).
// ---------------------------------------------------------------------------
template<bool EDGE>
__global__ __launch_bounds__(256, 2)
void msg_mfma_kernel(const float* __restrict__ hEin,
                     const int*   __restrict__ Eidx,
                     const float* __restrict__ mask_att,   // node only
                     const short* __restrict__ hvP,        // [2][L*128] bf16 planes
                     const short* __restrict__ WaT,        // [2][128][384]
                     const short* __restrict__ WbT,        // [2][128][128]
                     const short* __restrict__ WcT,        // [2][128][128]
                     const float* __restrict__ ba,
                     const float* __restrict__ bb,
                     const float* __restrict__ bc,
                     const float* __restrict__ ln_s,       // edge only
                     const float* __restrict__ ln_o,
                     float* __restrict__ outp)
{
    __shared__ union {
        short xc[2][2][96][40];   // double-buffered staging  61,440 B (union max)
        short cp[2][96][136];     // inter-layer acts         52,224 B
        float xb[96 * 132];       // EDGE residual for LN     50,688 B
    } sm;                         // 61,440 B + mask_s -> 2 blocks/CU (123.6/160 KB)
    __shared__ float mask_s[96];

    const int bid  = blockIdx.x;
    const int n0   = bid * 2;
    const int tid  = threadIdx.x;
    const int w    = tid >> 6;
    const int lane = tid & 63;
    const int lr   = lane & 15;
    const int hgr  = lane >> 4;
    // pi(lr): physical Cp row for logical A-row lr
    const int plr  = ((lr & 2) << 2) | ((2 * (lr >> 2) + (lr & 1) + 2 * (lr & 2)) & 7);
    const int colA = w * 32 + lr;
    const int colB = colA + 16;
    const int PL   = LDIM * HDIM;

    if constexpr (!EDGE) {
        if (tid < 96) mask_s[tid] = mask_att[(size_t)n0 * KNB + tid];
    }

    // staging task descriptors: 768 (row, col-quad) tasks, 3 per thread
    int xoff[3];            // short offset within one xc plane: row*40 + q*4
    int hvo[3], nbo[3];     // element offsets into hv planes
    const float* pE[3];
#pragma unroll
    for (int it = 0; it < 3; it++) {
        const int t = tid + it * 256, row = t >> 3, q = t & 7;
        xoff[it] = row * 40 + q * 4;
        const int node = n0 + (row >= 48 ? 1 : 0);
        hvo[it] = node * HDIM + q * 4;
        nbo[it] = Eidx[n0 * KNB + row] * HDIM + q * 4;
        pE[it]  = hEin + ((size_t)n0 * KNB + row) * HDIM + q * 4;
    }

    f32x4 acc[12];   // [mt][nt]: logical rows mt*16+hgr*4+j, col w*32+nt*16+lr

    uint4 sr[3];     // staged data in regs: seg1 = raw float4; else hi(xy)/lo(zw)
    auto LOADR = [&](int ks) {
#pragma unroll
        for (int it = 0; it < 3; it++) {
            const int seg = ks >> 2, co = (ks & 3) * 32;
            if (seg == 1) {
                sr[it] = *(const uint4*)(pE[it] + co);
            } else {
                const int base = (seg == 0 ? hvo[it] : nbo[it]) + co;
                const uint2 h = *(const uint2*)(hvP + base);
                const uint2 l = *(const uint2*)(hvP + PL + base);
                sr[it] = make_uint4(h.x, h.y, l.x, l.y);
            }
        }
    };
    auto WRITES = [&](int ks, int b) {
        short* p0 = &sm.xc[b][0][0][0];
        short* p1 = &sm.xc[b][1][0][0];
#pragma unroll
        for (int it = 0; it < 3; it++) {
            if ((ks >> 2) == 1) {
                const float4 v = *(const float4*)&sr[it];
                short h0,l0,h1,l1,h2,l2,h3,l3;
                split2(v.x,h0,l0); split2(v.y,h1,l1);
                split2(v.z,h2,l2); split2(v.w,h3,l3);
                *(short4*)(p0 + xoff[it]) = make_short4(h0,h1,h2,h3);
                *(short4*)(p1 + xoff[it]) = make_short4(l0,l1,l2,l3);
            } else {
                *(uint2*)(p0 + xoff[it]) = make_uint2(sr[it].x, sr[it].y);
                *(uint2*)(p1 + xoff[it]) = make_uint2(sr[it].z, sr[it].w);
            }
        }
    };
    auto BLOAD = [&](const short* Th, int stride, int ks,
                     bf16x8& b0, bf16x8& b1, bf16x8& b2, bf16x8& b3) {
        const short* Tl = Th + 128 * stride;
        const int ko = ks * 32 + hgr * 8;
        b0 = *(const bf16x8*)(Th + (size_t)colA * stride + ko);
        b1 = *(const bf16x8*)(Tl + (size_t)colA * stride + ko);
        b2 = *(const bf16x8*)(Th + (size_t)colB * stride + ko);
        b3 = *(const bf16x8*)(Tl + (size_t)colB * stride + ko);
    };
    // boundary: gelu + split + store to Cp at physically permuted rows
    auto storeC = [&]() {
#pragma unroll
        for (int mt = 0; mt < 6; mt++)
#pragma unroll
        for (int nt = 0; nt < 2; nt++) {
            const int col = w * 32 + nt * 16 + lr;
            const f32x4 a = acc[mt * 2 + nt];
#pragma unroll
            for (int j = 0; j < 4; j++) {
                // logical row r = hgr*4 + j -> physical mt*16 + pi(r)
                const int prw = mt * 16 +
                    (((j >> 1) << 3) | ((2 * hgr + (j & 1) + 4 * (j >> 1)) & 7));
                short h, l; split2(gelu_f(a[j]), h, l);
                sm.cp[0][prw][col] = h;
                sm.cp[1][prw][col] = l;
            }
        }
    };
    auto gemmK128 = [&](const short* T, const float* bias) {
        const float bA = bias[colA], bB = bias[colB];
#pragma unroll
        for (int mt = 0; mt < 6; mt++) {
            acc[mt*2+0] = (f32x4){bA, bA, bA, bA};
            acc[mt*2+1] = (f32x4){bB, bB, bB, bB};
        }
        bf16x8 c0,c1,c2,c3,d0,d1,d2,d3;
        BLOAD(T, 128, 0, c0,c1,c2,c3);
#pragma unroll 1
        for (int ks = 0; ks < 4; ks++) {
            if (ks < 3) BLOAD(T, 128, ks + 1, d0,d1,d2,d3);
            const int ko = ks * 32 + hgr * 8;
#pragma unroll
            for (int mt = 0; mt < 6; mt++) {
                bf16x8 ah = *(const bf16x8*)&sm.cp[0][mt*16 + plr][ko];
                bf16x8 al = *(const bf16x8*)&sm.cp[1][mt*16 + plr][ko];
                mm3(acc[mt*2+0], ah, al, c0, c1);
                mm3(acc[mt*2+1], ah, al, c2, c3);
            }
            c0=d0; c1=d1; c2=d2; c3=d3;
        }
    };

    // ======== layer 1: gelu(X @ Wa + ba), K = 384, staged+double-buffered ====
    {
        const float bA = ba[colA], bB = ba[colB];
#pragma unroll
        for (int mt = 0; mt < 6; mt++) {
            acc[mt*2+0] = (f32x4){bA, bA, bA, bA};
            acc[mt*2+1] = (f32x4){bB, bB, bB, bB};
        }
    }
    {
        bf16x8 c0,c1,c2,c3,d0,d1,d2,d3;
        LOADR(0);
        BLOAD(WaT, 384, 0, c0,c1,c2,c3);
        WRITES(0, 0);
        __syncthreads();
#pragma unroll 1
        for (int ks = 0; ks < 12; ks++) {
            if (ks < 11) { LOADR(ks + 1); BLOAD(WaT, 384, ks + 1, d0,d1,d2,d3); }
            const int b = ks & 1;
#pragma unroll
            for (int mt = 0; mt < 6; mt++) {
                bf16x8 ah = *(const bf16x8*)&sm.xc[b][0][mt*16 + lr][hgr*8];
                bf16x8 al = *(const bf16x8*)&sm.xc[b][1][mt*16 + lr][hgr*8];
                mm3(acc[mt*2+0], ah, al, c0, c1);
                mm3(acc[mt*2+1], ah, al, c2, c3);
            }
            if (ks < 11) WRITES(ks + 1, b ^ 1);
            __syncthreads();
            c0=d0; c1=d1; c2=d2; c3=d3;
        }
    }
    // Xc dead (post-barrier); overlay Cp
    storeC();
    __syncthreads();

    // ======== layer 2: gelu(C1 @ Wb + bb) ========
    gemmK128(WbT, bb);
    __syncthreads();          // all C1 reads done
    storeC();
    __syncthreads();

    // ======== layer 3: C2 @ Wc + bc ========
    gemmK128(WcT, bc);

    if constexpr (!EDGE) {
        float s[4] = {0.f, 0.f, 0.f, 0.f};   // [node][nt]
#pragma unroll
        for (int mt = 0; mt < 6; mt++) {
            const int nodei = (mt >= 3) ? 1 : 0;
#pragma unroll
            for (int j = 0; j < 4; j++) {
                const float m = mask_s[mt*16 + hgr*4 + j];
                s[nodei*2+0] = fmaf(m, acc[mt*2+0][j], s[nodei*2+0]);
                s[nodei*2+1] = fmaf(m, acc[mt*2+1][j], s[nodei*2+1]);
            }
        }
#pragma unroll
        for (int i = 0; i < 4; i++) {
            s[i] += __shfl_xor(s[i], 16, 64);
            s[i] += __shfl_xor(s[i], 32, 64);
        }
        if (lane < 16) {
            outp[(size_t)n0 * HDIM + colA]     = s[0] * (1.0f / 30.0f);
            outp[(size_t)n0 * HDIM + colB]     = s[1] * (1.0f / 30.0f);
            outp[(size_t)(n0+1) * HDIM + colA] = s[2] * (1.0f / 30.0f);
            outp[(size_t)(n0+1) * HDIM + colB] = s[3] * (1.0f / 30.0f);
        }
    } else {
        __syncthreads();      // Cp reads done; overlay xb (logical rows)
#pragma unroll
        for (int mt = 0; mt < 6; mt++)
#pragma unroll
        for (int nt = 0; nt < 2; nt++) {
            const int col = w*32 + nt*16 + lr;
            const f32x4 a = acc[mt*2+nt];
#pragma unroll
            for (int j = 0; j < 4; j++) {
                const int row = mt*16 + hgr*4 + j;
                const float he = hEin[((size_t)n0 * KNB + row) * HDIM + col];
                sm.xb[row * 132 + col] = a[j] + he;
            }
        }
        __syncthreads();
        for (int r = w; r < 96; r += 4) {
            const float x0 = sm.xb[r * 132 + lane];
            const float x1 = sm.xb[r * 132 + 64 + lane];
            float su = x0 + x1;
#pragma unroll
            for (int off = 32; off; off >>= 1) su += __shfl_xor(su, off, 64);
            const float mu = su * (1.0f / 128.0f);
            const float d0 = x0 - mu, d1 = x1 - mu;
            float v = d0 * d0 + d1 * d1;
#pragma unroll
            for (int off = 32; off; off >>= 1) v += __shfl_xor(v, off, 64);
            const float rs = rsqrtf(v * (1.0f / 128.0f) + 1e-5f);
            const size_t base = ((size_t)n0 * KNB + r) * HDIM;
            outp[base + lane]      = d0 * rs * ln_s[lane]      + ln_o[lane];
            outp[base + 64 + lane] = d1 * rs * ln_s[64 + lane] + ln_o[64 + lane];
        }
    }
}

// ---------------------------------------------------------------------------
// fp32 register-tiled GEMM helper (K2 + fallback)
// ---------------------------------------------------------------------------
template<int RT, int KDIM>
__device__ __forceinline__ void gemm_block(
    const float* __restrict__ A, const int lda,
    const float* __restrict__ Wg, const int wstride,
    float* __restrict__ Wst,
    float acc[RT][4], const int rg, const int jg, const int tid)
{
#pragma unroll 1
    for (int ci = 0; ci < KDIM / 32; ci++) {
        __syncthreads();
#pragma unroll
        for (int e = tid; e < 1024; e += 256) {
            const int i  = e >> 5;
            const int j4 = (e & 31) << 2;
            *(float4*)(Wst + i * 128 + j4) =
                *(const float4*)(Wg + (size_t)(ci * 32 + i) * wstride + j4);
        }
        __syncthreads();
#pragma unroll
        for (int ii = 0; ii < 32; ii += 4) {
            float4 xr[RT];
#pragma unroll
            for (int rr = 0; rr < RT; rr++)
                xr[rr] = *(const float4*)(A + (rg * RT + rr) * lda + ci * 32 + ii);
#pragma unroll
            for (int q = 0; q < 4; q++) {
                const float4 wv = *(const float4*)(Wst + (ii + q) * 128 + (jg << 2));
#pragma unroll
                for (int rr = 0; rr < RT; rr++) {
                    const float x = (q == 0) ? xr[rr].x : (q == 1) ? xr[rr].y
                                  : (q == 2) ? xr[rr].z : xr[rr].w;
                    acc[rr][0] = fmaf(x, wv.x, acc[rr][0]);
                    acc[rr][1] = fmaf(x, wv.y, acc[rr][1]);
                    acc[rr][2] = fmaf(x, wv.z, acc[rr][2]);
                    acc[rr][3] = fmaf(x, wv.w, acc[rr][3]);
                }
            }
        }
    }
}

// K2: LN1(hV + dh) -> FFN -> LN2 -> mask. NODES per block.
template<int NODES, int RT, int NPART>
__global__ __launch_bounds__(256, 2)
void node_update_kernel(const float* __restrict__ hV,
                        const float* __restrict__ dhp,   // [L][NPART][128]
                        const float* __restrict__ maskV,
                        const float* __restrict__ Wi, const float* __restrict__ bi,
                        const float* __restrict__ Wo, const float* __restrict__ bo,
                        const float* __restrict__ n1s, const float* __restrict__ n1o,
                        const float* __restrict__ n2s, const float* __restrict__ n2o,
                        float* __restrict__ outp)
{
    __shared__ float hv1[NODES * 128];
    __shared__ float Wst[32 * 128];
    __shared__ float tb[NODES * 128];

    const int l0  = blockIdx.x * NODES;
    const int tid = threadIdx.x;
    const int w = tid >> 6, ln = tid & 63;

    for (int r = w; r < NODES; r += 4) {
        const int l = l0 + r;
        const size_t b = (size_t)l * 128;
        float x0 = hV[b + ln], x1 = hV[b + 64 + ln];
#pragma unroll
        for (int p = 0; p < NPART; p++) {
            x0 += dhp[((size_t)l * NPART + p) * 128 + ln];
            x1 += dhp[((size_t)l * NPART + p) * 128 + 64 + ln];
        }
        float s = x0 + x1;
#pragma unroll
        for (int off = 32; off; off >>= 1) s += __shfl_xor(s, off, 64);
        const float mu = s * (1.0f / 128.0f);
        const float d0 = x0 - mu, d1 = x1 - mu;
        float v = d0 * d0 + d1 * d1;
#pragma unroll
        for (int off = 32; off; off >>= 1) v += __shfl_xor(v, off, 64);
        const float rs = rsqrtf(v * (1.0f / 128.0f) + 1e-5f);
        hv1[r * 128 + ln]      = d0 * rs * n1s[ln]      + n1o[ln];
        hv1[r * 128 + 64 + ln] = d1 * rs * n1s[64 + ln] + n1o[64 + ln];
    }

    const int rg = tid >> 5, jg = tid & 31;
    float dacc[RT][4];
#pragma unroll
    for (int rr = 0; rr < RT; rr++)
#pragma unroll
        for (int q = 0; q < 4; q++) dacc[rr][q] = bo[(jg << 2) + q];

#pragma unroll 1
    for (int hc = 0; hc < 4; hc++) {
        float tacc[RT][4];
#pragma unroll
        for (int rr = 0; rr < RT; rr++)
#pragma unroll
            for (int q = 0; q < 4; q++) tacc[rr][q] = bi[hc * 128 + (jg << 2) + q];
        gemm_block<RT, 128>(hv1, 128, Wi + hc * 128, 512, Wst, tacc, rg, jg, tid);
        __syncthreads();
#pragma unroll
        for (int rr = 0; rr < RT; rr++)
#pragma unroll
            for (int q = 0; q < 4; q++)
                tb[(rg * RT + rr) * 128 + (jg << 2) + q] = gelu_f(tacc[rr][q]);
        gemm_block<RT, 128>(tb, 128, Wo + (size_t)hc * 128 * 128, 128, Wst, dacc, rg, jg, tid);
    }
    __syncthreads();
#pragma unroll
    for (int rr = 0; rr < RT; rr++)
#pragma unroll
        for (int q = 0; q < 4; q++)
            tb[(rg * RT + rr) * 128 + (jg << 2) + q] = dacc[rr][q];
    __syncthreads();

    for (int r = w; r < NODES; r += 4) {
        const int l = l0 + r;
        const float x0 = hv1[r * 128 + ln]      + tb[r * 128 + ln];
        const float x1 = hv1[r * 128 + 64 + ln] + tb[r * 128 + 64 + ln];
        float s = x0 + x1;
#pragma unroll
        for (int off = 32; off; off >>= 1) s += __shfl_xor(s, off, 64);
        const float mu = s * (1.0f / 128.0f);
        const float d0 = x0 - mu, d1 = x1 - mu;
        float v = d0 * d0 + d1 * d1;
#pragma unroll
        for (int off = 32; off; off >>= 1) v += __shfl_xor(v, off, 64);
        const float rs = rsqrtf(v * (1.0f / 128.0f) + 1e-5f);
        const float mv = maskV[l];
        outp[(size_t)l * 128 + ln]      = mv * (d0 * rs * n2s[ln]      + n2o[ln]);
        outp[(size_t)l * 128 + 64 + ln] = mv * (d1 * rs * n2s[64 + ln] + n2o[64 + ln]);
    }
}

// ---------------------------------------------------------------------------
// Fallback fp32 message kernel (only if ws too small)
// ---------------------------------------------------------------------------
template<bool EDGE>
__global__ __launch_bounds__(256, 2)
void msg_kernel(const float* __restrict__ hv_src,
                const float* __restrict__ hEin,
                const int*   __restrict__ Eidx,
                const float* __restrict__ mask_att,
                const float* __restrict__ Wa, const float* __restrict__ ba,
                const float* __restrict__ Wb, const float* __restrict__ bb,
                const float* __restrict__ Wc3, const float* __restrict__ bc,
                const float* __restrict__ ln_s, const float* __restrict__ ln_o,
                float* __restrict__ outp)
{
    __shared__ float xs[24 * 384];
    __shared__ float Wst[32 * 128];
    __shared__ float Cb[24 * 128];

    const int bid = blockIdx.x;
    const int l   = bid >> 1;
    const int k0  = (bid & 1) * 24;
    const int tid = threadIdx.x;

#pragma unroll
    for (int e = tid; e < 24 * 32; e += 256) {
        const int r  = e >> 5;
        const int c4 = (e & 31) << 2;
        const int k  = k0 + r;
        const int nidx = Eidx[l * KNB + k];
        const float4 hv4 = *(const float4*)(hv_src + (size_t)l * HDIM + c4);
        const float4 he4 = *(const float4*)(hEin + ((size_t)l * KNB + k) * HDIM + c4);
        const float4 nb4 = *(const float4*)(hv_src + (size_t)nidx * HDIM + c4);
        *(float4*)(xs + r * 384 +       c4) = hv4;
        *(float4*)(xs + r * 384 + 128 + c4) = he4;
        *(float4*)(xs + r * 384 + 256 + c4) = nb4;
    }

    const int rg = tid >> 5;
    const int jg = tid & 31;
    float acc[3][4];

#pragma unroll
    for (int rr = 0; rr < 3; rr++)
#pragma unroll
        for (int q = 0; q < 4; q++) acc[rr][q] = ba[(jg << 2) + q];
    gemm_block<3, 384>(xs, 384, Wa, 128, Wst, acc, rg, jg, tid);
    __syncthreads();
#pragma unroll
    for (int rr = 0; rr < 3; rr++)
#pragma unroll
        for (int q = 0; q < 4; q++)
            Cb[(rg * 3 + rr) * 128 + (jg << 2) + q] = gelu_f(acc[rr][q]);

#pragma unroll
    for (int rr = 0; rr < 3; rr++)
#pragma unroll
        for (int q = 0; q < 4; q++) acc[rr][q] = bb[(jg << 2) + q];
    gemm_block<3, 128>(Cb, 128, Wb, 128, Wst, acc, rg, jg, tid);
    __syncthreads();
#pragma unroll
    for (int rr = 0; rr < 3; rr++)
#pragma unroll
        for (int q = 0; q < 4; q++)
            Cb[(rg * 3 + rr) * 128 + (jg << 2) + q] = gelu_f(acc[rr][q]);

#pragma unroll
    for (int rr = 0; rr < 3; rr++)
#pragma unroll
        for (int q = 0; q < 4; q++) acc[rr][q] = bc[(jg << 2) + q];
    gemm_block<3, 128>(Cb, 128, Wc3, 128, Wst, acc, rg, jg, tid);
    __syncthreads();

    if constexpr (!EDGE) {
        float psum[4] = {0.f, 0.f, 0.f, 0.f};
#pragma unroll
        for (int rr = 0; rr < 3; rr++) {
            const int k = k0 + rg * 3 + rr;
            const float mval = mask_att[l * KNB + k];
#pragma unroll
            for (int q = 0; q < 4; q++) psum[q] = fmaf(mval, acc[rr][q], psum[q]);
        }
#pragma unroll
        for (int q = 0; q < 4; q++) Cb[rg * 128 + (jg << 2) + q] = psum[q];
        __syncthreads();
        if (tid < 128) {
            float s = 0.f;
#pragma unroll
            for (int g = 0; g < 8; g++) s += Cb[g * 128 + tid];
            outp[(size_t)bid * 128 + tid] = s * (1.0f / 30.0f);
        }
    } else {
#pragma unroll
        for (int rr = 0; rr < 3; rr++)
#pragma unroll
            for (int q = 0; q < 4; q++)
                Cb[(rg * 3 + rr) * 128 + (jg << 2) + q] = acc[rr][q];
        __syncthreads();
        const int w = tid >> 6, ln = tid & 63;
        for (int r = w; r < 24; r += 4) {
            const float x0 = Cb[r * 128 + ln]      + xs[r * 384 + 128 + ln];
            const float x1 = Cb[r * 128 + 64 + ln] + xs[r * 384 + 192 + ln];
            float s = x0 + x1;
#pragma unroll
            for (int off = 32; off; off >>= 1) s += __shfl_xor(s, off, 64);
            const float mu = s * (1.0f / 128.0f);
            const float d0 = x0 - mu, d1 = x1 - mu;
            float v = d0 * d0 + d1 * d1;
#pragma unroll
            for (int off = 32; off; off >>= 1) v += __shfl_xor(v, off, 64);
            const float rs = rsqrtf(v * (1.0f / 128.0f) + 1e-5f);
            const size_t base = ((size_t)(l * KNB + k0 + r)) * 128;
            outp[base + ln]      = d0 * rs * ln_s[ln]      + ln_o[ln];
            outp[base + 64 + ln] = d1 * rs * ln_s[64 + ln] + ln_o[64 + ln];
        }
    }
}

extern "C" void kernel_launch(void* const* d_in, const int* in_sizes, int n_in,
                              void* d_out, int out_size, void* d_ws, size_t ws_size,
                              hipStream_t stream) {
    const float* hV      = (const float*)d_in[0];
    const float* hE      = (const float*)d_in[1];
    const int*   Eidx    = (const int*)  d_in[2];
    const float* maskV   = (const float*)d_in[3];
    const float* maskAtt = (const float*)d_in[4];
    const float* W1  = (const float*)d_in[5];  const float* b1  = (const float*)d_in[6];
    const float* W2  = (const float*)d_in[7];  const float* b2  = (const float*)d_in[8];
    const float* W3  = (const float*)d_in[9];  const float* b3  = (const float*)d_in[10];
    const float* W11 = (const float*)d_in[11]; const float* b11 = (const float*)d_in[12];
    const float* W12 = (const float*)d_in[13]; const float* b12 = (const float*)d_in[14];
    const float* W13 = (const float*)d_in[15]; const float* b13 = (const float*)d_in[16];
    const float* Wi  = (const float*)d_in[17]; const float* bi  = (const float*)d_in[18];
    const float* Wo  = (const float*)d_in[19]; const float* bo  = (const float*)d_in[20];
    const float* n1s = (const float*)d_in[21]; const float* n1o = (const float*)d_in[22];
    const float* n2s = (const float*)d_in[23]; const float* n2o = (const float*)d_in[24];
    const float* n3s = (const float*)d_in[25]; const float* n3o = (const float*)d_in[26];

    float* outF  = (float*)d_out;
    float* hVout = outF;                          // [L][128]
    float* hEout = outF + (size_t)LDIM * HDIM;    // [L][48][128]

    // ws layout: 6 weight planes + dh + hv planes
    const size_t O_W1T  = 0;          // [2][128][384] bf16 = 196608 B
    const size_t O_W2T  = 196608;
    const size_t O_W3T  = 262144;
    const size_t O_W11T = 327680;
    const size_t O_W12T = 524288;
    const size_t O_W13T = 589824;
    const size_t O_DH   = 655360;                         // [L][128] f32
    const size_t O_HVP  = O_DH + (size_t)LDIM*HDIM*4;     // [2][L*128] bf16
    const size_t WS_NEED = O_HVP + (size_t)2*LDIM*HDIM*2; // 8,847,360 B

    if (ws_size >= WS_NEED) {
        char* wsb = (char*)d_ws;
        short* W1T  = (short*)(wsb + O_W1T);
        short* W2T  = (short*)(wsb + O_W2T);
        short* W3T  = (short*)(wsb + O_W3T);
        short* W11T = (short*)(wsb + O_W11T);
        short* W12T = (short*)(wsb + O_W12T);
        short* W13T = (short*)(wsb + O_W13T);
        float* dh   = (float*)(wsb + O_DH);
        short* hvP  = (short*)(wsb + O_HVP);

        wsplit_kernel<<<192, 256, 0, stream>>>(W1,  W1T,  384);
        wsplit_kernel<<< 64, 256, 0, stream>>>(W2,  W2T,  128);
        wsplit_kernel<<< 64, 256, 0, stream>>>(W3,  W3T,  128);
        wsplit_kernel<<<192, 256, 0, stream>>>(W11, W11T, 384);
        wsplit_kernel<<< 64, 256, 0, stream>>>(W12, W12T, 128);
        wsplit_kernel<<< 64, 256, 0, stream>>>(W13, W13T, 128);
        hvsplit_kernel<<<(LDIM*HDIM + 255)/256, 256, 0, stream>>>(hV, hvP);

        msg_mfma_kernel<false><<<LDIM / 2, 256, 0, stream>>>(
            hE, Eidx, maskAtt, hvP, W1T, W2T, W3T, b1, b2, b3, nullptr, nullptr, dh);

        node_update_kernel<16, 2, 1><<<LDIM / 16, 256, 0, stream>>>(
            hV, dh, maskV, Wi, bi, Wo, bo, n1s, n1o, n2s, n2o, hVout);

        hvsplit_kernel<<<(LDIM*HDIM + 255)/256, 256, 0, stream>>>(hVout, hvP);

        msg_mfma_kernel<true><<<LDIM / 2, 256, 0, stream>>>(
            hE, Eidx, nullptr, hvP, W11T, W12T, W13T, b11, b12, b13, n3s, n3o, hEout);
    } else {
        // fallback: pure fp32 path
        const size_t dh_bytes = (size_t)LDIM * 2 * HDIM * sizeof(float);
        float* dhp = (ws_size >= dh_bytes) ? (float*)d_ws : hEout;

        msg_kernel<false><<<LDIM * 2, 256, 0, stream>>>(
            hV, hE, Eidx, maskAtt, W1, b1, W2, b2, W3, b3, nullptr, nullptr, dhp);

        node_update_kernel<32, 4, 2><<<LDIM / 32, 256, 0, stream>>>(
            hV, dhp, maskV, Wi, bi, Wo, bo, n1s, n1o, n2s, n2o, hVout);

        msg_kernel<true><<<LDIM * 2, 256, 0, stream>>>(
            hVout, hE, Eidx, nullptr, W11, b11, W12, b12, W13, b13, n3s, n3o, hEout);
    }
}